// Round 4
// baseline (36.569 us; speedup 1.0000x reference)
//
#include <hip/hip_runtime.h>
#include <math.h>

// Problem constants (match reference)
constexpr int B_ = 32, Q_ = 500, N_ = 200, K_ = 16, C_ = 92;
constexpr int TWO_K = 2 * K_;        // 32
constexpr int QT = 64;               // q per block (lane dimension)
constexpr int NG = 50;               // n per block (200 = 4 * 50, no tail)
constexpr int WAVES = 8;
constexpr int THREADS = 64 * WAVES;  // 512
constexpr int PS = 93;               // sProb row stride (odd -> 2-way free gather)
constexpr int OS = 51;               // sOut row stride (odd -> 2-way free)
constexpr float EPS_ = 1e-6f;
constexpr float POLY_SCALE = 5.0f / 32.0f;   // POLY_COST / (2K)

__global__ __launch_bounds__(THREADS)
void matcher_cost_kernel(const float* __restrict__ logits,   // (B,Q,C)
                         const float* __restrict__ ppoly,    // (B,Q,K,2)
                         const int*   __restrict__ labels,   // (B,N)
                         const float* __restrict__ tpoly,    // (B,N,K,2)
                         float* __restrict__ out)            // (B,Q,N)
{
    __shared__ float sProb[QT * PS];   // per-q class probs        (23808 B)
    __shared__ float sOut[QT * OS];    // output tile [q][n]       (13056 B)
    __shared__ float sTB[NG * 5];      // target bbox+area          (1000 B)
    // ~37.9 KB -> 4 blocks/CU by LDS

    const int tid  = threadIdx.x;
    const int w    = tid >> 6;         // wave id
    const int lane = tid & 63;
    const int qt   = blockIdx.x;       // 0..7
    const int ng   = blockIdx.y;       // 0..3
    const int b    = blockIdx.z;       // 0..31
    const int q0   = qt * QT;
    const int n0   = ng * NG;

    // ---------- phase 0a: softmax for the block's 64 q (8 threads per q) ----------
    {
        int g = tid >> 3, sub = tid & 7;              // g: local q, sub: class slice
        int qq = q0 + g; if (qq >= Q_) qq = Q_ - 1;   // clamp (tile 7 tail)
        const float* lg = logits + ((size_t)(b * Q_ + qq)) * C_;
        float v[12]; float mx = -INFINITY;
        #pragma unroll
        for (int m = 0; m < 12; ++m) {
            int c = sub + 8 * m;
            if (c < C_) { v[m] = lg[c]; mx = fmaxf(mx, v[m]); } else v[m] = -INFINITY;
        }
        #pragma unroll
        for (int off = 4; off; off >>= 1) mx = fmaxf(mx, __shfl_xor(mx, off, 8));
        float s = 0.0f;
        #pragma unroll
        for (int m = 0; m < 12; ++m) {
            int c = sub + 8 * m;
            if (c < C_) { v[m] = __expf(v[m] - mx); s += v[m]; }
        }
        #pragma unroll
        for (int off = 4; off; off >>= 1) s += __shfl_xor(s, off, 8);
        float rs = 1.0f / s;
        #pragma unroll
        for (int m = 0; m < 12; ++m) {
            int c = sub + 8 * m;
            if (c < C_) sProb[g * PS + c] = v[m] * rs;
        }
    }

    // ---------- phase 0b: target bboxes for the block's 50 n (8 threads per n) ----------
    {
        int g = tid >> 3, sub = tid & 7;
        if (g < NG) {
            const float4* tr = reinterpret_cast<const float4*>(
                tpoly + ((size_t)(b * N_ + n0 + g)) * TWO_K);
            float4 p = tr[sub];
            float xm = fminf(p.x, p.z), xM = fmaxf(p.x, p.z);
            float ym = fminf(p.y, p.w), yM = fmaxf(p.y, p.w);
            #pragma unroll
            for (int off = 4; off; off >>= 1) {
                xm = fminf(xm, __shfl_xor(xm, off, 8));
                xM = fmaxf(xM, __shfl_xor(xM, off, 8));
                ym = fminf(ym, __shfl_xor(ym, off, 8));
                yM = fmaxf(yM, __shfl_xor(yM, off, 8));
            }
            if (sub == 0) {
                sTB[g * 5 + 0] = xm; sTB[g * 5 + 1] = ym;
                sTB[g * 5 + 2] = xM; sTB[g * 5 + 3] = yM;
                sTB[g * 5 + 4] = (xM - xm) * (yM - ym);
            }
        }
    }

    // ---------- phase 0c: per-thread pred polyline (q = q0 + lane) ----------
    int qc = q0 + lane; if (qc >= Q_) qc = Q_ - 1;    // clamp; masked at store
    float px[K_], py[K_];
    float pxm = INFINITY, pxM = -INFINITY, pym = INFINITY, pyM = -INFINITY;
    {
        const float4* pr = reinterpret_cast<const float4*>(
            ppoly + ((size_t)(b * Q_ + qc)) * TWO_K);
        #pragma unroll
        for (int j = 0; j < 8; ++j) {
            float4 v = pr[j];
            px[2 * j] = v.x;  py[2 * j] = v.y;
            px[2 * j + 1] = v.z; py[2 * j + 1] = v.w;
            pxm = fminf(pxm, fminf(v.x, v.z)); pxM = fmaxf(pxM, fmaxf(v.x, v.z));
            pym = fminf(pym, fminf(v.y, v.w)); pyM = fmaxf(pyM, fmaxf(v.y, v.w));
        }
    }
    const float parea = (pxM - pxm) * (pyM - pym);
    __syncthreads();

    const int probbase = lane * PS;

    // ---------- phase 1: wave-uniform n loop; targets via scalar loads ----------
    for (int nn = w; nn < NG; nn += WAVES) {
        const int nu = __builtin_amdgcn_readfirstlane(n0 + nn);  // force uniform
        const float* __restrict__ tr = tpoly + ((size_t)(b * N_ + nu)) * TWO_K;
        float ts[TWO_K];
        #pragma unroll
        for (int j = 0; j < TWO_K; ++j) ts[j] = tr[j];           // -> s_load (SGPRs)
        const int lbl = labels[b * N_ + nu];                     // uniform -> s_load

        float f0 = 0, f1 = 0, r0 = 0, r1 = 0;
        #pragma unroll
        for (int k = 0; k < K_; ++k) {
            float tx = ts[2 * k], ty = ts[2 * k + 1];
            float af = fabsf(px[k] - tx) + fabsf(py[k] - ty);
            float ar = fabsf(px[K_ - 1 - k] - tx) + fabsf(py[K_ - 1 - k] - ty);
            if (k & 1) { f1 += af; r1 += ar; } else { f0 += af; r0 += ar; }
        }
        float cpoly = fminf(f0 + f1, r0 + r1);

        float cclass = -sProb[probbase + lbl];                   // 2-way free gather

        float tx0 = sTB[nn * 5 + 0], ty0 = sTB[nn * 5 + 1];
        float tx1 = sTB[nn * 5 + 2], ty1 = sTB[nn * 5 + 3];
        float tarea = sTB[nn * 5 + 4];
        float ix0 = fmaxf(pxm, tx0), iy0 = fmaxf(pym, ty0);
        float ix1 = fminf(pxM, tx1), iy1 = fminf(pyM, ty1);
        float iw = fmaxf(ix1 - ix0, 0.0f), ih = fmaxf(iy1 - iy0, 0.0f);
        float inter = iw * ih;
        float uni = parea + tarea - inter;
        float iou = inter / fmaxf(uni, EPS_);
        float cx0 = fminf(pxm, tx0), cy0 = fminf(pym, ty0);
        float cx1 = fmaxf(pxM, tx1), cy1 = fmaxf(pyM, ty1);
        float ca = (cx1 - cx0) * (cy1 - cy0);
        float giou = iou - (ca - uni) / fmaxf(ca, EPS_);

        sOut[lane * OS + nn] = fmaf(cpoly, POLY_SCALE, cclass) - giou;
    }
    __syncthreads();

    // ---------- phase 2: coalesced store of the [64 q][50 n] tile ----------
    for (int r = w; r < QT; r += WAVES) {
        int q = q0 + r;
        if (q < Q_ && lane < NG)
            out[((size_t)(b * Q_ + q)) * N_ + n0 + lane] = sOut[r * OS + lane];
    }
}

extern "C" void kernel_launch(void* const* d_in, const int* in_sizes, int n_in,
                              void* d_out, int out_size, void* d_ws, size_t ws_size,
                              hipStream_t stream) {
    const float* logits = (const float*)d_in[0];   // (B,Q,C)
    const float* ppoly  = (const float*)d_in[1];   // (B,Q,K,2)
    const int*   labels = (const int*)d_in[2];     // (B,N)
    const float* tpoly  = (const float*)d_in[3];   // (B,N,K,2)
    float* out = (float*)d_out;                    // (B,Q,N)

    dim3 grid((Q_ + QT - 1) / QT, N_ / NG, B_);    // (8, 4, 32)
    matcher_cost_kernel<<<grid, THREADS, 0, stream>>>(logits, ppoly, labels, tpoly, out);
}

// Round 5
// 34.054 us; speedup vs baseline: 1.0738x; 1.0738x over previous
//
#include <hip/hip_runtime.h>
#include <math.h>

// Problem constants (match reference)
constexpr int B_ = 32, Q_ = 500, N_ = 200, K_ = 16, C_ = 92;
constexpr int TWO_K = 2 * K_;        // 32
constexpr int QT = 16;               // q per block (2 per wave)
constexpr int WAVES = 8;
constexpr int THREADS = 64 * WAVES;  // 512
constexpr int TPAD = 34;             // padded row stride (floats), even for b64
constexpr int PS = 93;               // sProb row stride
constexpr float EPS_ = 1e-6f;
constexpr float POLY_SCALE = 5.0f / 32.0f;   // POLY_COST / (2K)

__device__ __forceinline__ float rfl(float v) {
    return __int_as_float(__builtin_amdgcn_readfirstlane(__float_as_int(v)));
}
__device__ __forceinline__ float rcpf_(float x) { return __builtin_amdgcn_rcpf(x); }
__device__ __forceinline__ float ad(float2 p, float2 t) {
    return fabsf(p.x - t.x) + fabsf(p.y - t.y);   // sub,sub,add(|.|,|.|) = 3 VALU
}

__global__ __launch_bounds__(THREADS, 4)
void matcher_cost_kernel(const float* __restrict__ logits,   // (B,Q,C)
                         const float* __restrict__ ppoly,    // (B,Q,K,2)
                         const int*   __restrict__ labels,   // (B,N)
                         const float* __restrict__ tpoly,    // (B,N,K,2)
                         float* __restrict__ out)            // (B,Q,N)
{
    __shared__ float sT[N_ * TPAD];     // 27200 B target polylines
    __shared__ float sP[QT * TPAD];     //  2176 B pred polylines (block tile)
    __shared__ float sTB[N_ * 5];       //  4000 B tgt bbox+area
    __shared__ float sPB[QT * 5];       //   320 B pred bbox+area
    __shared__ float sProb[QT * PS];    //  5952 B class probs
    __shared__ int   sLbl[N_];          //   800 B
    // total 40448 B -> exactly 4 blocks/CU

    const int tid  = threadIdx.x;
    const int w    = tid >> 6;
    const int lane = tid & 63;
    const int b    = blockIdx.y;
    const int q0   = blockIdx.x * QT;

    // ---------------- phase 0: stage + softmax ----------------
    {
        const float* tb = tpoly + (size_t)b * (N_ * TWO_K);
        for (int u = tid; u < N_ * TWO_K / 4; u += THREADS) {
            float4 v = reinterpret_cast<const float4*>(tb)[u];
            int n = u >> 3, j = (u & 7) * 4;
            float* d = &sT[n * TPAD + j];
            reinterpret_cast<float2*>(d)[0] = make_float2(v.x, v.y);
            reinterpret_cast<float2*>(d)[1] = make_float2(v.z, v.w);
        }
        if (tid < QT * TWO_K / 4) {     // 128 threads stage preds
            int ql = tid >> 3, j = (tid & 7) * 4;
            int q = min(q0 + ql, Q_ - 1);
            float4 v = reinterpret_cast<const float4*>(
                ppoly + (size_t)(b * Q_ + q) * TWO_K)[tid & 7];
            float* d = &sP[ql * TPAD + j];
            reinterpret_cast<float2*>(d)[0] = make_float2(v.x, v.y);
            reinterpret_cast<float2*>(d)[1] = make_float2(v.z, v.w);
        }
        for (int n = tid; n < N_; n += THREADS) sLbl[n] = labels[b * N_ + n];

        // softmax: 16 half-wave groups, one per q
        int qi = tid >> 5, l32 = tid & 31;
        int q = min(q0 + qi, Q_ - 1);
        const float* lg = logits + (size_t)(b * Q_ + q) * C_;
        float lv[3]; float m = -INFINITY;
        #pragma unroll
        for (int j = 0; j < 3; ++j) {
            int c = l32 + 32 * j;
            lv[j] = (c < C_) ? lg[c] : -INFINITY;
            m = fmaxf(m, lv[j]);
        }
        #pragma unroll
        for (int off = 16; off; off >>= 1) m = fmaxf(m, __shfl_xor(m, off, 32));
        float s = 0.0f;
        #pragma unroll
        for (int j = 0; j < 3; ++j) {
            int c = l32 + 32 * j;
            if (c < C_) { float e = __expf(lv[j] - m); lv[j] = e; s += e; }
        }
        #pragma unroll
        for (int off = 16; off; off >>= 1) s += __shfl_xor(s, off, 32);
        float rs = 1.0f / s;
        #pragma unroll
        for (int j = 0; j < 3; ++j) {
            int c = l32 + 32 * j;
            if (c < C_) sProb[qi * PS + c] = lv[j] * rs;
        }
    }
    __syncthreads();

    // ---------------- phase 1: bboxes ----------------
    for (int n = tid; n < N_; n += THREADS) {      // threads 0..199
        const float2* tr = reinterpret_cast<const float2*>(&sT[n * TPAD]);
        float xm = INFINITY, ym = INFINITY, xM = -INFINITY, yM = -INFINITY;
        #pragma unroll
        for (int k = 0; k < K_; ++k) {
            float2 t = tr[k];
            xm = fminf(xm, t.x); xM = fmaxf(xM, t.x);
            ym = fminf(ym, t.y); yM = fmaxf(yM, t.y);
        }
        sTB[n * 5 + 0] = xm; sTB[n * 5 + 1] = ym;
        sTB[n * 5 + 2] = xM; sTB[n * 5 + 3] = yM;
        sTB[n * 5 + 4] = (xM - xm) * (yM - ym);
    }
    if (tid >= 256 && tid < 256 + QT) {            // wave 4: pred bboxes
        int ql = tid - 256;
        const float2* pr = reinterpret_cast<const float2*>(&sP[ql * TPAD]);
        float xm = INFINITY, ym = INFINITY, xM = -INFINITY, yM = -INFINITY;
        #pragma unroll
        for (int k = 0; k < K_; ++k) {
            float2 p = pr[k];
            xm = fminf(xm, p.x); xM = fmaxf(xM, p.x);
            ym = fminf(ym, p.y); yM = fmaxf(yM, p.y);
        }
        sPB[ql * 5 + 0] = xm; sPB[ql * 5 + 1] = ym;
        sPB[ql * 5 + 2] = xM; sPB[ql * 5 + 3] = yM;
        sPB[ql * 5 + 4] = (xM - xm) * (yM - ym);
    }
    __syncthreads();

    // ---------------- phase 2: main loop (wave = 2 q, lane = n) ----------------
    const int qlA = 2 * w, qlB = 2 * w + 1;
    const int qA = q0 + qlA, qB = q0 + qlB;
    if (qA >= Q_) return;                          // fully-invalid wave (no barriers below)
    const bool vB = (qB < Q_);

    // pred bbox scalars -> SGPR (broadcast read + readfirstlane)
    const float Axm = rfl(sPB[qlA * 5 + 0]), Aym = rfl(sPB[qlA * 5 + 1]);
    const float AxM = rfl(sPB[qlA * 5 + 2]), AyM = rfl(sPB[qlA * 5 + 3]);
    const float Aar = rfl(sPB[qlA * 5 + 4]);
    const float Bxm = rfl(sPB[qlB * 5 + 0]), Bym = rfl(sPB[qlB * 5 + 1]);
    const float BxM = rfl(sPB[qlB * 5 + 2]), ByM = rfl(sPB[qlB * 5 + 3]);
    const float Bar = rfl(sPB[qlB * 5 + 4]);

    const float2* pa = reinterpret_cast<const float2*>(&sP[qlA * TPAD]);
    const float2* pb = reinterpret_cast<const float2*>(&sP[qlB * TPAD]);
    float* outA = out + (size_t)(b * Q_ + qA) * N_;
    float* outB = out + (size_t)(b * Q_ + min(qB, Q_ - 1)) * N_;

    for (int i = 0; i < 4; ++i) {
        int n_ = 64 * i + lane;
        int nn = min(n_, N_ - 1);                  // clamp reads; guard stores
        const float2* tr = reinterpret_cast<const float2*>(&sT[nn * TPAD]);

        float fA0 = 0, fA1 = 0, rA0 = 0, rA1 = 0;
        float fB0 = 0, fB1 = 0, rB0 = 0, rB1 = 0;
        #pragma unroll
        for (int k = 0; k < 8; ++k) {
            const int k2 = 15 - k;
            float2 t1 = tr[k],  t2 = tr[k2];       // per-lane, shared by both q
            float2 a1 = pa[k],  a2 = pa[k2];       // uniform -> broadcast
            float2 b1 = pb[k],  b2 = pb[k2];
            fA0 += ad(a1, t1);  fA1 += ad(a2, t2); // fwd terms k, 15-k
            rA0 += ad(a2, t1);  rA1 += ad(a1, t2); // rev terms k, 15-k
            fB0 += ad(b1, t1);  fB1 += ad(b2, t2);
            rB0 += ad(b2, t1);  rB1 += ad(b1, t2);
        }
        float cpA = fminf(fA0 + fA1, rA0 + rA1);
        float cpB = fminf(fB0 + fB1, rB0 + rB1);

        int lbl = sLbl[nn];
        float prA = sProb[qlA * PS + lbl];
        float prB = sProb[qlB * PS + lbl];

        float tx0 = sTB[nn * 5 + 0], ty0 = sTB[nn * 5 + 1];
        float tx1 = sTB[nn * 5 + 2], ty1 = sTB[nn * 5 + 3];
        float ta  = sTB[nn * 5 + 4];

        // GIoU A
        float ix0 = fmaxf(Axm, tx0), iy0 = fmaxf(Aym, ty0);
        float ix1 = fminf(AxM, tx1), iy1 = fminf(AyM, ty1);
        float iw = fmaxf(ix1 - ix0, 0.0f), ih = fmaxf(iy1 - iy0, 0.0f);
        float inter = iw * ih;
        float uni = Aar + ta - inter;
        float iou = inter * rcpf_(fmaxf(uni, EPS_));
        float cx0 = fminf(Axm, tx0), cy0 = fminf(Aym, ty0);
        float cx1 = fmaxf(AxM, tx1), cy1 = fmaxf(AyM, ty1);
        float ca = (cx1 - cx0) * (cy1 - cy0);
        float giouA = iou - (ca - uni) * rcpf_(fmaxf(ca, EPS_));

        // GIoU B
        float jx0 = fmaxf(Bxm, tx0), jy0 = fmaxf(Bym, ty0);
        float jx1 = fminf(BxM, tx1), jy1 = fminf(ByM, ty1);
        float jw = fmaxf(jx1 - jx0, 0.0f), jh = fmaxf(jy1 - jy0, 0.0f);
        float interB = jw * jh;
        float uniB = Bar + ta - interB;
        float iouB = interB * rcpf_(fmaxf(uniB, EPS_));
        float dx0 = fminf(Bxm, tx0), dy0 = fminf(Bym, ty0);
        float dx1 = fmaxf(BxM, tx1), dy1 = fmaxf(ByM, ty1);
        float cb = (dx1 - dx0) * (dy1 - dy0);
        float giouB = iouB - (cb - uniB) * rcpf_(fmaxf(cb, EPS_));

        float oA = fmaf(cpA, POLY_SCALE, -prA) - giouA;
        float oB = fmaf(cpB, POLY_SCALE, -prB) - giouB;
        if (n_ < N_) {
            outA[n_] = oA;
            if (vB) outB[n_] = oB;
        }
    }
}

extern "C" void kernel_launch(void* const* d_in, const int* in_sizes, int n_in,
                              void* d_out, int out_size, void* d_ws, size_t ws_size,
                              hipStream_t stream) {
    const float* logits = (const float*)d_in[0];   // (B,Q,C)
    const float* ppoly  = (const float*)d_in[1];   // (B,Q,K,2)
    const int*   labels = (const int*)d_in[2];     // (B,N)
    const float* tpoly  = (const float*)d_in[3];   // (B,N,K,2)
    float* out = (float*)d_out;                    // (B,Q,N)

    dim3 grid((Q_ + QT - 1) / QT, B_);             // (32, 32)
    matcher_cost_kernel<<<grid, THREADS, 0, stream>>>(logits, ppoly, labels, tpoly, out);
}